// Round 22
// baseline (62.187 us; speedup 1.0000x reference)
//
#include <hip/hip_runtime.h>
#include <stdint.h>

// VQ: inputs (16,64,64,64) f32 BCHW, codebook (1024,64) f32.
// out[0:65536] = argmin indices as float; out[65536:] = gathered rows, BCHW.
//
// r22 = r21 with 512-thread blocks (NPB=128, 8 waves): per-wave shape is
// byte-identical (64 pos x 256 codes, VGPR ~80), but residency quantization
// improves (VGPR-80 bracket allows 6 waves/SIMD; 8-wave blocks -> 3
// blocks/CU = 24 waves/CU vs r21's 16) and block-level fixed costs halve.
// ws_size-aware cbT placement (no carve when ws fits). All numerics
// r12-r21-validated.
#define NUM_K 1024
#define CDIM  64
#define NPOS  65536
#define NPB   128
#define BIAS  0.25f          // s = cnorm+BIAS-2dot in [0.08,0.42] > 0
#define QS    4194304.0f     // 2^22: key = trunc(s*QS)<<10 | k fits u32
#define ILIM  128            // quantized gap < 128*2^-22 ~ 3.05e-5 -> rescreen
#define CARVE_N0 61440       // positions n>=61440 are b==15
#define CBT0  3997696        // out idx: carved cbT location (fallback path)
#define WS_CBT 270336        // ws byte offset for cbT when ws is large
#define WS_CBT_NEED 532480   // 270336 + 262144

typedef __attribute__((ext_vector_type(8))) short short8;
typedef __attribute__((ext_vector_type(4))) float f32x4;

union U4S8 { uint4 u; short8 s; };

// ---- d_ws layout (bytes) ----
#define WS_CNORM 0           // 1024 f32 exact
#define WS_CNQ   4096        // 1024 f32: (cnorm + BIAS) * QS
#define WS_CBF   8192        // 64 ktiles * 4096 B = [8192, 270336)

__device__ __forceinline__ void cvt_pair(float f0, float f1,
                                         uint32_t& hp, uint32_t& lp) {
    uint32_t h;
    asm("v_cvt_pk_bf16_f32 %0, %1, %2" : "=v"(h) : "v"(f0), "v"(f1));
    float h0 = __uint_as_float(h << 16);
    float h1 = __uint_as_float(h & 0xFFFF0000u);
    float r0 = f0 - h0, r1 = f1 - h1;
    uint32_t l;
    asm("v_cvt_pk_bf16_f32 %0, %1, %2" : "=v"(l) : "v"(r0), "v"(r1));
    hp = h; lp = l;
}

__device__ __forceinline__ unsigned long long shflxor64(unsigned long long v, int off) {
    unsigned lo = (unsigned)v, hi = (unsigned)(v >> 32);
    lo = (unsigned)__shfl_xor((int)lo, off);
    hi = (unsigned)__shfl_xor((int)hi, off);
    return ((unsigned long long)hi << 32) | lo;
}

// ---- K1: cnorm + cnq + bf16 frag split + cbT ----
__global__ __launch_bounds__(64) void vq_prep_kernel(
    const float* __restrict__ cb, unsigned char* __restrict__ ws,
    float* __restrict__ cbt) {
#pragma clang fp contract(off)
    const int k = blockIdx.x * 64 + threadIdx.x;    // grid = 16 blocks
    const float4* row4 = (const float4*)(cb + k * CDIM);
    float v[CDIM];
#pragma unroll
    for (int i = 0; i < 16; ++i) {
        float4 t = row4[i];
        v[i * 4 + 0] = t.x; v[i * 4 + 1] = t.y;
        v[i * 4 + 2] = t.z; v[i * 4 + 3] = t.w;
    }
    float r[8];
#pragma unroll
    for (int j = 0; j < 8; ++j) r[j] = v[j] * v[j];
#pragma unroll
    for (int i = 1; i < 8; ++i) {
#pragma unroll
        for (int j = 0; j < 8; ++j) {
            float s = v[i * 8 + j] * v[i * 8 + j];
            r[j] = r[j] + s;
        }
    }
    const float cn =
        ((r[0] + r[1]) + (r[2] + r[3])) + ((r[4] + r[5]) + (r[6] + r[7]));
    ((float*)(ws + WS_CNORM))[k] = cn;
    ((float*)(ws + WS_CNQ))[k]   = (cn + BIAS) * QS;

    // transposed f32 codebook (coalesced per c across block)
#pragma unroll 8
    for (int c = 0; c < CDIM; ++c)
        cbt[c * 1024 + k] = v[c];

    const int kt = k >> 4, rr = k & 15;
    unsigned char* base = ws + WS_CBF + kt * 4096;
#pragma unroll
    for (int s = 0; s < 8; ++s) {
        U4S8 H, L;
        uint32_t hp, lp;
        cvt_pair(v[s * 8 + 0], v[s * 8 + 1], hp, lp); H.u.x = hp; L.u.x = lp;
        cvt_pair(v[s * 8 + 2], v[s * 8 + 3], hp, lp); H.u.y = hp; L.u.y = lp;
        cvt_pair(v[s * 8 + 4], v[s * 8 + 5], hp, lp); H.u.z = hp; L.u.z = lp;
        cvt_pair(v[s * 8 + 6], v[s * 8 + 7], hp, lp); H.u.w = hp; L.u.w = lp;
        const int ks   = s >> 2;
        const int lane = (s & 3) * 16 + rr;
        unsigned char* hi_dst = base + ks * 2048 + lane * 16;
        *(uint4*)(hi_dst)        = H.u;
        *(uint4*)(hi_dst + 1024) = L.u;
    }
}

#define MFMA16(A, B, C) __builtin_amdgcn_mfma_f32_16x16x32_bf16(A, B, C, 0, 0, 0)

#define LOADT(H0, L0, H1, L1, addr) {                   \
    const unsigned char* fb_ = (addr);                  \
    H0.u = *(const uint4*)(fb_);                        \
    L0.u = *(const uint4*)(fb_ + 1024);                 \
    H1.u = *(const uint4*)(fb_ + 2048);                 \
    L1.u = *(const uint4*)(fb_ + 3072);                 \
}

// 4 n-frags, 2 independent 3-MFMA chains each (8 chains/ktile)
#define COMPT(H0, L0, H1, L1, KT) {                                           \
    const int kb_ = (kq * 16 + (KT)) * 16 + lg * 4;                           \
    const f32x4 cq_ = *(const f32x4*)(cnq_g + kb_);                           \
    _Pragma("unroll")                                                         \
    for (int na = 0; na < 4; ++na) {                                          \
        f32x4 p0 = {0.f,0.f,0.f,0.f}, p1 = {0.f,0.f,0.f,0.f};                 \
        p0 = MFMA16(L0.s, zfh[na][0], p0);                                    \
        p1 = MFMA16(L1.s, zfh[na][1], p1);                                    \
        p0 = MFMA16(H0.s, zfl[na][0], p0);                                    \
        p1 = MFMA16(H1.s, zfl[na][1], p1);                                    \
        p0 = MFMA16(H0.s, zfh[na][0], p0);                                    \
        p1 = MFMA16(H1.s, zfh[na][1], p1);                                    \
        f32x4 a_;                                                             \
        a_[0] = p0[0] + p1[0]; a_[1] = p0[1] + p1[1];                         \
        a_[2] = p0[2] + p1[2]; a_[3] = p0[3] + p1[3];                         \
        _Pragma("unroll")                                                     \
        for (int r = 0; r < 4; r += 2) {                                      \
            uint32_t ka = ((uint32_t)fmaf(-2.0f * QS, a_[r],     cq_[r])     << 10) | (uint32_t)(kb_ + r);     \
            uint32_t kc = ((uint32_t)fmaf(-2.0f * QS, a_[r + 1], cq_[r + 1]) << 10) | (uint32_t)(kb_ + r + 1); \
            uint32_t lo_ = min(ka, kc), hi_ = max(ka, kc);                    \
            m2[na] = min(min(m2[na], hi_), max(lo_, m1[na]));                 \
            m1[na] = min(m1[na], lo_);                                        \
        }                                                                     \
    }                                                                         \
}

// ---- K2: filter + inline rescreen + zis + zqs ----
__global__ __launch_bounds__(512, 3) void vq_filter_kernel(
    const float* __restrict__ in, const float* __restrict__ cb,
    const unsigned char* __restrict__ ws, float* __restrict__ out,
    const float* __restrict__ cbT, int carve) {
#pragma clang fp contract(off)
    const int tid  = threadIdx.x;
    const int lane = tid & 63;
    const int wv   = tid >> 6;          // 0..7
    const int kq   = wv & 3;            // k-quarter
    const int nh   = wv >> 2;           // n-half (0/1): positions nh*64..+63
    const int l15  = lane & 15;
    const int lg   = lane >> 4;         // 0..3
    const int n0g  = blockIdx.x * NPB;  // grid = 512 blocks
    const int b    = n0g >> 12;
    const int hw0  = n0g & 4095;

    __shared__ uint2 wred[NPB][5];
    __shared__ int   sfin[NPB];
    __shared__ int   ambcnt;
    __shared__ int   amblist[NPB];
    // union: phase A = z staging (zhi 16384 | zlo 16384), phase B = rescreen
    // z rows (8 x 64 f32), phase C = tile[128][65] (33280 B)
    __shared__ __align__(16) unsigned char zs[NPB * 65 * 4];

    const unsigned char* cbf = ws + WS_CBF;
    const float* cnq_g = (const float*)(ws + WS_CNQ);

    if (tid == 0) ambcnt = 0;

    // ---- shared z staging: 1024 tasks (128 pos x 8 slots), 2/thread ----
#pragma unroll
    for (int it = 0; it < 2; ++it) {
        const int pos  = tid & 127;
        const int slot = (tid >> 7) + 4 * it;
        const float* zp = in + (((size_t)(b * CDIM + slot * 8)) << 12) + hw0 + pos;
        float f[8];
#pragma unroll
        for (int j = 0; j < 8; ++j) f[j] = zp[(size_t)j << 12];
        U4S8 H, L;
        uint32_t hp, lp;
        cvt_pair(f[0], f[1], hp, lp); H.u.x = hp; L.u.x = lp;
        cvt_pair(f[2], f[3], hp, lp); H.u.y = hp; L.u.y = lp;
        cvt_pair(f[4], f[5], hp, lp); H.u.z = hp; L.u.z = lp;
        cvt_pair(f[6], f[7], hp, lp); H.u.w = hp; L.u.w = lp;
        const int byte = pos * 128 + ((slot * 16) ^ ((pos & 7) * 16));
        *(uint4*)(zs + byte)         = H.u;
        *(uint4*)(zs + 16384 + byte) = L.u;
    }
    __syncthreads();

    // ---- each wave reads its 16 z fragments from LDS (its n-half) ----
    short8 zfh[4][2], zfl[4][2];   // [na][ks]
#pragma unroll
    for (int na = 0; na < 4; ++na) {
        const int pos = nh * 64 + na * 16 + l15;
        const int psw = (pos & 7) * 16;
#pragma unroll
        for (int ks = 0; ks < 2; ++ks) {
            const int slot = ks * 4 + lg;
            const int byte = pos * 128 + ((slot * 16) ^ psw);
            zfh[na][ks] = *(const short8*)(zs + byte);
            zfl[na][ks] = *(const short8*)(zs + 16384 + byte);
        }
    }
    __syncthreads();   // z staging region dead

    uint32_t m1[4] = {0xFFFFFFFFu, 0xFFFFFFFFu, 0xFFFFFFFFu, 0xFFFFFFFFu};
    uint32_t m2[4] = {0xFFFFFFFFu, 0xFFFFFFFFu, 0xFFFFFFFFu, 0xFFFFFFFFu};

    // ---- main loop: 16 ktiles, depth-2 register prefetch (A/B sets) ----
    const unsigned char* qb = cbf + (size_t)kq * 65536 + (size_t)lane * 16;
    U4S8 Ah0, Al0, Ah1, Al1, Bh0, Bl0, Bh1, Bl1;
    LOADT(Ah0, Al0, Ah1, Al1, qb);
    LOADT(Bh0, Bl0, Bh1, Bl1, qb + 4096);

#pragma unroll
    for (int kt = 0; kt < 16; kt += 2) {
        U4S8 Nh0, Nl0, Nh1, Nl1, Mh0, Ml0, Mh1, Ml1;
        if (kt + 2 < 16) LOADT(Nh0, Nl0, Nh1, Nl1, qb + (kt + 2) * 4096);
        COMPT(Ah0, Al0, Ah1, Al1, kt);
        if (kt + 3 < 16) LOADT(Mh0, Ml0, Mh1, Ml1, qb + (kt + 3) * 4096);
        COMPT(Bh0, Bl0, Bh1, Bl1, kt + 1);
        Ah0 = Nh0; Al0 = Nl0; Ah1 = Nh1; Al1 = Nl1;
        Bh0 = Mh0; Bl0 = Ml0; Bh1 = Mh1; Bl1 = Ml1;
    }

    // ---- merge the 4 lane-groups (quarter complete per wave) ----
#pragma unroll
    for (int na = 0; na < 4; ++na) {
#pragma unroll
        for (int off = 16; off <= 32; off <<= 1) {
            uint32_t o1 = (uint32_t)__shfl_xor((int)m1[na], off);
            uint32_t o2 = (uint32_t)__shfl_xor((int)m2[na], off);
            m2[na] = min(min(m2[na], o2), max(m1[na], o1));
            m1[na] = min(m1[na], o1);
        }
    }

    if (lg == 0) {
#pragma unroll
        for (int na = 0; na < 4; ++na) {
            uint2 w; w.x = m1[na]; w.y = m2[na];
            wred[nh * 64 + na * 16 + l15][kq] = w;
        }
    }
    __syncthreads();

    // ---- cross-wave merge, zis write, LOCAL flagging ----
    if (tid < NPB) {
        uint32_t c1 = 0xFFFFFFFFu, c2 = 0xFFFFFFFFu;
#pragma unroll
        for (int w = 0; w < 4; ++w) {
            uint2 v = wred[tid][w];
            c2 = min(c2, min(v.y, max(c1, v.x)));
            c1 = min(c1, v.x);
        }
        const int idx = (int)(c1 & 1023u);
        sfin[tid] = idx;
        out[n0g + tid] = (float)idx;
        if ((c2 >> 10) - (c1 >> 10) < ILIM) {
            int p = atomicAdd(&ambcnt, 1);
            amblist[p] = tid;
        }
    }
    __syncthreads();

    // ---- inline exact rescreen (coalesced cbT path, r14-validated) ----
    const int namb = ambcnt;
    if (namb > 0) {
        const float* cnorm = (const float*)(ws + WS_CNORM);
        float* zrow = (float*)zs + wv * 64;       // staging region is dead
        for (int i = wv; i < namb; i += 8) {
            const int nloc = amblist[i];
            const int n  = n0g + nloc;
            const int hw = hw0 + nloc;
            float zc = in[(((size_t)(b * CDIM + lane)) << 12) + hw];
            // bit-exact numpy pairwise znorm via shfl (r7-validated)
            float sq = zc * zc;
            float accp = sq;
#pragma unroll
            for (int i2 = 1; i2 < 8; ++i2)
                accp = accp + __shfl(sq, i2 * 8 + (lane & 7));
            float t1 = accp + __shfl_xor(accp, 1);
            float t2 = t1 + __shfl_xor(t1, 2);
            float t3 = t2 + __shfl_xor(t2, 4);
            const float zn = __shfl(t3, 0);
            zrow[lane] = zc;
            // lane owns codes j*256 + 4*lane + r; coalesced float4 columns
            f32x4 acc0 = {0.f,0.f,0.f,0.f}, acc1 = {0.f,0.f,0.f,0.f};
            f32x4 acc2 = {0.f,0.f,0.f,0.f}, acc3 = {0.f,0.f,0.f,0.f};
#pragma unroll 4
            for (int c = 0; c < CDIM; ++c) {
                const float zv = zrow[c];
                const float* col = cbT + c * 1024 + 4 * lane;
                f32x4 q0 = *(const f32x4*)(col);
                f32x4 q1 = *(const f32x4*)(col + 256);
                f32x4 q2 = *(const f32x4*)(col + 512);
                f32x4 q3 = *(const f32x4*)(col + 768);
#pragma unroll
                for (int r = 0; r < 4; ++r) {
                    acc0[r] = fmaf(zv, q0[r], acc0[r]);
                    acc1[r] = fmaf(zv, q1[r], acc1[r]);
                    acc2[r] = fmaf(zv, q2[r], acc2[r]);
                    acc3[r] = fmaf(zv, q3[r], acc3[r]);
                }
            }
            unsigned long long bestk = ~0ull;
#pragma unroll
            for (int j = 0; j < 4; ++j) {
                const f32x4 cnv = *(const f32x4*)(cnorm + j * 256 + 4 * lane);
                const f32x4 acc = (j == 0) ? acc0 : (j == 1) ? acc1
                                 : (j == 2) ? acc2 : acc3;
#pragma unroll
                for (int r = 0; r < 4; ++r) {
                    const int k = j * 256 + 4 * lane + r;
                    float t = zn + cnv[r];     // fl(znorm + cnorm)
                    float u = 2.0f * acc[r];   // fl(2*dot)
                    float d = t - u;           // fl(t - u)
                    unsigned long long key =
                        ((unsigned long long)__float_as_uint(d) << 10) | (unsigned)k;
                    bestk = key < bestk ? key : bestk;
                }
            }
#pragma unroll
            for (int off = 32; off >= 1; off >>= 1) {
                unsigned long long o = shflxor64(bestk, off);
                bestk = o < bestk ? o : bestk;
            }
            if (lane == 0) {
                const int idx = (int)(bestk & 1023u);
                out[n] = (float)idx;
                sfin[nloc] = idx;
            }
        }
    }
    __syncthreads();

    if (carve && b == 15) return;   // carved image: patch rebuilds it

    // ---- zqs epilogue: gather via corrected sfin -> tile -> BCHW ----
    float (*tile)[65] = (float (*)[65])zs;
    {
        const int p = tid >> 2, q4 = tid & 3;   // p 0..127, 16 ch each
        const int idx = sfin[p];
        const float4* row = (const float4*)(cb + (size_t)idx * CDIM) + q4 * 4;
#pragma unroll
        for (int i = 0; i < 4; ++i) {
            float4 v = row[i];
            const int cch = q4 * 16 + i * 4;
            tile[p][cch + 0] = v.x; tile[p][cch + 1] = v.y;
            tile[p][cch + 2] = v.z; tile[p][cch + 3] = v.w;
        }
    }
    __syncthreads();
    {
        const int pos = tid & 127, cg = tid >> 7;   // cg 0..3
        float* zq = out + NPOS + (((size_t)b * CDIM) << 12) + hw0;
#pragma unroll
        for (int i = 0; i < 16; ++i) {
            const int cch = i * 4 + cg;
            zq[((size_t)cch << 12) + pos] = tile[pos][cch];
        }
    }
}

// ---- K3 (carve fallback only): rebuild b=15 zqs image from final zis ----
__global__ __launch_bounds__(256) void vq_patch_kernel(
    const float* __restrict__ cb, float* __restrict__ out) {
    const int tid  = threadIdx.x;
    const int lane = tid & 63;
    const int wv   = tid >> 6;
    const int p0   = CARVE_N0 + blockIdx.x * 64;   // grid = 64 blocks
    const int hw0  = p0 & 4095;

    __shared__ float tile[64][65];
    __shared__ int sfin[64];
    if (tid < 64) sfin[tid] = (int)out[p0 + tid];
    __syncthreads();
    {
        const int p = tid >> 2, q4 = tid & 3;
        const int idx = sfin[p];
        const float4* row = (const float4*)(cb + (size_t)idx * CDIM) + q4 * 4;
#pragma unroll
        for (int i = 0; i < 4; ++i) {
            float4 v = row[i];
            const int cch = q4 * 16 + i * 4;
            tile[p][cch + 0] = v.x; tile[p][cch + 1] = v.y;
            tile[p][cch + 2] = v.z; tile[p][cch + 3] = v.w;
        }
    }
    __syncthreads();
    {
        float* zq = out + NPOS + (((size_t)15 * CDIM) << 12) + hw0;
#pragma unroll
        for (int i = 0; i < 16; ++i) {
            const int cch = i * 4 + wv;
            zq[((size_t)cch << 12) + lane] = tile[lane][cch];
        }
    }
}

extern "C" void kernel_launch(void* const* d_in, const int* in_sizes, int n_in,
                              void* d_out, int out_size, void* d_ws, size_t ws_size,
                              hipStream_t stream) {
    const float* in = (const float*)d_in[0];   // 16*64*64*64
    const float* cb = (const float*)d_in[1];   // 1024*64
    float* out = (float*)d_out;                // 65536 + 4194304
    unsigned char* ws = (unsigned char*)d_ws;

    const int carve = (ws_size < (size_t)WS_CBT_NEED) ? 1 : 0;
    float* cbt = carve ? (out + CBT0) : (float*)(ws + WS_CBT);

    vq_prep_kernel<<<16, 64, 0, stream>>>(cb, ws, cbt);
    vq_filter_kernel<<<NPOS / NPB, 512, 0, stream>>>(in, cb, ws, out, cbt, carve);
    if (carve)
        vq_patch_kernel<<<64, 256, 0, stream>>>(cb, out);
}

// Round 23
// 54.481 us; speedup vs baseline: 1.1414x; 1.1414x over previous
//
#include <hip/hip_runtime.h>
#include <stdint.h>

// VQ: inputs (16,64,64,64) f32 BCHW, codebook (1024,64) f32.
// out[0:65536] = argmin indices as float; out[65536:] = gathered rows, BCHW.
//
// r23 = r21 verbatim (measured best: 54.5 µs). r22's 8-wave variant
// regressed (worse residency quantization); r21's shape is the measured
// optimum across r15-r22's A/B sweep of chains/amortization/staging/
// occupancy/prefetch-depth/block-size.
//  K1 prep: cnorm + cnq + bf16 hi/lo frag split in ws + cbT.
//  K2 filter: NPB=64, 4 waves, depth-2 prefetch, 8 independent 3-MFMA
//     chains, int keys, inline exact rescreen (coalesced cbT, bit-exact
//     numpy znorm, t/u/d order, u64 first-occurrence keys), zqs epilogue.
//  cbT in ws when ws_size allows (no carve/patch); else r18 carve fallback.
#define NUM_K 1024
#define CDIM  64
#define NPOS  65536
#define NPB   64
#define BIAS  0.25f          // s = cnorm+BIAS-2dot in [0.08,0.42] > 0
#define QS    4194304.0f     // 2^22: key = trunc(s*QS)<<10 | k fits u32
#define ILIM  128            // quantized gap < 128*2^-22 ~ 3.05e-5 -> rescreen
#define CARVE_N0 61440       // positions n>=61440 are b==15
#define CBT0  3997696        // out idx: carved cbT location (fallback path)
#define WS_CBT 270336        // ws byte offset for cbT when ws is large
#define WS_CBT_NEED 532480   // 270336 + 262144

typedef __attribute__((ext_vector_type(8))) short short8;
typedef __attribute__((ext_vector_type(4))) float f32x4;

union U4S8 { uint4 u; short8 s; };

// ---- d_ws layout (bytes) ----
#define WS_CNORM 0           // 1024 f32 exact
#define WS_CNQ   4096        // 1024 f32: (cnorm + BIAS) * QS
#define WS_CBF   8192        // 64 ktiles * 4096 B = [8192, 270336)

__device__ __forceinline__ void cvt_pair(float f0, float f1,
                                         uint32_t& hp, uint32_t& lp) {
    uint32_t h;
    asm("v_cvt_pk_bf16_f32 %0, %1, %2" : "=v"(h) : "v"(f0), "v"(f1));
    float h0 = __uint_as_float(h << 16);
    float h1 = __uint_as_float(h & 0xFFFF0000u);
    float r0 = f0 - h0, r1 = f1 - h1;
    uint32_t l;
    asm("v_cvt_pk_bf16_f32 %0, %1, %2" : "=v"(l) : "v"(r0), "v"(r1));
    hp = h; lp = l;
}

__device__ __forceinline__ unsigned long long shflxor64(unsigned long long v, int off) {
    unsigned lo = (unsigned)v, hi = (unsigned)(v >> 32);
    lo = (unsigned)__shfl_xor((int)lo, off);
    hi = (unsigned)__shfl_xor((int)hi, off);
    return ((unsigned long long)hi << 32) | lo;
}

// ---- K1: cnorm + cnq + bf16 frag split + cbT ----
__global__ __launch_bounds__(64) void vq_prep_kernel(
    const float* __restrict__ cb, unsigned char* __restrict__ ws,
    float* __restrict__ cbt) {
#pragma clang fp contract(off)
    const int k = blockIdx.x * 64 + threadIdx.x;    // grid = 16 blocks
    const float4* row4 = (const float4*)(cb + k * CDIM);
    float v[CDIM];
#pragma unroll
    for (int i = 0; i < 16; ++i) {
        float4 t = row4[i];
        v[i * 4 + 0] = t.x; v[i * 4 + 1] = t.y;
        v[i * 4 + 2] = t.z; v[i * 4 + 3] = t.w;
    }
    float r[8];
#pragma unroll
    for (int j = 0; j < 8; ++j) r[j] = v[j] * v[j];
#pragma unroll
    for (int i = 1; i < 8; ++i) {
#pragma unroll
        for (int j = 0; j < 8; ++j) {
            float s = v[i * 8 + j] * v[i * 8 + j];
            r[j] = r[j] + s;
        }
    }
    const float cn =
        ((r[0] + r[1]) + (r[2] + r[3])) + ((r[4] + r[5]) + (r[6] + r[7]));
    ((float*)(ws + WS_CNORM))[k] = cn;
    ((float*)(ws + WS_CNQ))[k]   = (cn + BIAS) * QS;

    // transposed f32 codebook (coalesced per c across block)
#pragma unroll 8
    for (int c = 0; c < CDIM; ++c)
        cbt[c * 1024 + k] = v[c];

    const int kt = k >> 4, rr = k & 15;
    unsigned char* base = ws + WS_CBF + kt * 4096;
#pragma unroll
    for (int s = 0; s < 8; ++s) {
        U4S8 H, L;
        uint32_t hp, lp;
        cvt_pair(v[s * 8 + 0], v[s * 8 + 1], hp, lp); H.u.x = hp; L.u.x = lp;
        cvt_pair(v[s * 8 + 2], v[s * 8 + 3], hp, lp); H.u.y = hp; L.u.y = lp;
        cvt_pair(v[s * 8 + 4], v[s * 8 + 5], hp, lp); H.u.z = hp; L.u.z = lp;
        cvt_pair(v[s * 8 + 6], v[s * 8 + 7], hp, lp); H.u.w = hp; L.u.w = lp;
        const int ks   = s >> 2;
        const int lane = (s & 3) * 16 + rr;
        unsigned char* hi_dst = base + ks * 2048 + lane * 16;
        *(uint4*)(hi_dst)        = H.u;
        *(uint4*)(hi_dst + 1024) = L.u;
    }
}

#define MFMA16(A, B, C) __builtin_amdgcn_mfma_f32_16x16x32_bf16(A, B, C, 0, 0, 0)

#define LOADT(H0, L0, H1, L1, addr) {                   \
    const unsigned char* fb_ = (addr);                  \
    H0.u = *(const uint4*)(fb_);                        \
    L0.u = *(const uint4*)(fb_ + 1024);                 \
    H1.u = *(const uint4*)(fb_ + 2048);                 \
    L1.u = *(const uint4*)(fb_ + 3072);                 \
}

// 4 n-frags, 2 independent 3-MFMA chains each (8 chains/ktile)
#define COMPT(H0, L0, H1, L1, KT) {                                           \
    const int kb_ = (wv * 16 + (KT)) * 16 + lg * 4;                           \
    const f32x4 cq_ = *(const f32x4*)(cnq_g + kb_);                           \
    _Pragma("unroll")                                                         \
    for (int na = 0; na < 4; ++na) {                                          \
        f32x4 p0 = {0.f,0.f,0.f,0.f}, p1 = {0.f,0.f,0.f,0.f};                 \
        p0 = MFMA16(L0.s, zfh[na][0], p0);                                    \
        p1 = MFMA16(L1.s, zfh[na][1], p1);                                    \
        p0 = MFMA16(H0.s, zfl[na][0], p0);                                    \
        p1 = MFMA16(H1.s, zfl[na][1], p1);                                    \
        p0 = MFMA16(H0.s, zfh[na][0], p0);                                    \
        p1 = MFMA16(H1.s, zfh[na][1], p1);                                    \
        f32x4 a_;                                                             \
        a_[0] = p0[0] + p1[0]; a_[1] = p0[1] + p1[1];                         \
        a_[2] = p0[2] + p1[2]; a_[3] = p0[3] + p1[3];                         \
        _Pragma("unroll")                                                     \
        for (int r = 0; r < 4; r += 2) {                                      \
            uint32_t ka = ((uint32_t)fmaf(-2.0f * QS, a_[r],     cq_[r])     << 10) | (uint32_t)(kb_ + r);     \
            uint32_t kc = ((uint32_t)fmaf(-2.0f * QS, a_[r + 1], cq_[r + 1]) << 10) | (uint32_t)(kb_ + r + 1); \
            uint32_t lo_ = min(ka, kc), hi_ = max(ka, kc);                    \
            m2[na] = min(min(m2[na], hi_), max(lo_, m1[na]));                 \
            m1[na] = min(m1[na], lo_);                                        \
        }                                                                     \
    }                                                                         \
}

// ---- K2: filter + inline rescreen + zis + zqs ----
__global__ __launch_bounds__(256, 3) void vq_filter_kernel(
    const float* __restrict__ in, const float* __restrict__ cb,
    const unsigned char* __restrict__ ws, float* __restrict__ out,
    const float* __restrict__ cbT, int carve) {
#pragma clang fp contract(off)
    const int tid  = threadIdx.x;
    const int lane = tid & 63;
    const int wv   = tid >> 6;          // 0..3 = k-quarter
    const int l15  = lane & 15;
    const int lg   = lane >> 4;         // 0..3
    const int n0g  = blockIdx.x * NPB;  // grid = 1024 blocks
    const int b    = n0g >> 12;
    const int hw0  = n0g & 4095;

    __shared__ uint2 wred[NPB][5];
    __shared__ int   sfin[NPB];
    __shared__ int   ambcnt;
    __shared__ int   amblist[NPB];
    // union: phase A = z staging (zhi 8192 | zlo 8192), phase B = rescreen
    // z rows (4 x 64 f32), phase C = tile[64][65]
    __shared__ __align__(16) unsigned char zs[NPB * 65 * 4];

    const unsigned char* cbf = ws + WS_CBF;
    const float* cnq_g = (const float*)(ws + WS_CNQ);

    if (tid == 0) ambcnt = 0;

    // ---- shared z staging: 512 tasks (64 pos x 8 slots), once per block ----
#pragma unroll
    for (int it = 0; it < 2; ++it) {
        const int pos  = tid & 63;
        const int slot = (tid >> 6) + 4 * it;
        const float* zp = in + (((size_t)(b * CDIM + slot * 8)) << 12) + hw0 + pos;
        float f[8];
#pragma unroll
        for (int j = 0; j < 8; ++j) f[j] = zp[(size_t)j << 12];
        U4S8 H, L;
        uint32_t hp, lp;
        cvt_pair(f[0], f[1], hp, lp); H.u.x = hp; L.u.x = lp;
        cvt_pair(f[2], f[3], hp, lp); H.u.y = hp; L.u.y = lp;
        cvt_pair(f[4], f[5], hp, lp); H.u.z = hp; L.u.z = lp;
        cvt_pair(f[6], f[7], hp, lp); H.u.w = hp; L.u.w = lp;
        const int byte = pos * 128 + ((slot * 16) ^ ((pos & 7) * 16));
        *(uint4*)(zs + byte)        = H.u;
        *(uint4*)(zs + 8192 + byte) = L.u;
    }
    __syncthreads();

    // ---- each wave reads its 16 z fragments from LDS ----
    short8 zfh[4][2], zfl[4][2];   // [na][ks]
#pragma unroll
    for (int na = 0; na < 4; ++na) {
        const int pos = na * 16 + l15;
        const int psw = (pos & 7) * 16;
#pragma unroll
        for (int ks = 0; ks < 2; ++ks) {
            const int slot = ks * 4 + lg;
            const int byte = pos * 128 + ((slot * 16) ^ psw);
            zfh[na][ks] = *(const short8*)(zs + byte);
            zfl[na][ks] = *(const short8*)(zs + 8192 + byte);
        }
    }
    __syncthreads();   // z staging region dead

    uint32_t m1[4] = {0xFFFFFFFFu, 0xFFFFFFFFu, 0xFFFFFFFFu, 0xFFFFFFFFu};
    uint32_t m2[4] = {0xFFFFFFFFu, 0xFFFFFFFFu, 0xFFFFFFFFu, 0xFFFFFFFFu};

    // ---- main loop: 16 ktiles, depth-2 register prefetch (A/B sets) ----
    const unsigned char* qb = cbf + (size_t)wv * 65536 + (size_t)lane * 16;
    U4S8 Ah0, Al0, Ah1, Al1, Bh0, Bl0, Bh1, Bl1;
    LOADT(Ah0, Al0, Ah1, Al1, qb);
    LOADT(Bh0, Bl0, Bh1, Bl1, qb + 4096);

#pragma unroll
    for (int kt = 0; kt < 16; kt += 2) {
        U4S8 Nh0, Nl0, Nh1, Nl1, Mh0, Ml0, Mh1, Ml1;
        if (kt + 2 < 16) LOADT(Nh0, Nl0, Nh1, Nl1, qb + (kt + 2) * 4096);
        COMPT(Ah0, Al0, Ah1, Al1, kt);
        if (kt + 3 < 16) LOADT(Mh0, Ml0, Mh1, Ml1, qb + (kt + 3) * 4096);
        COMPT(Bh0, Bl0, Bh1, Bl1, kt + 1);
        Ah0 = Nh0; Al0 = Nl0; Ah1 = Nh1; Al1 = Nl1;
        Bh0 = Mh0; Bl0 = Ml0; Bh1 = Mh1; Bl1 = Ml1;
    }

    // ---- merge the 4 lane-groups (quarter complete per wave) ----
#pragma unroll
    for (int na = 0; na < 4; ++na) {
#pragma unroll
        for (int off = 16; off <= 32; off <<= 1) {
            uint32_t o1 = (uint32_t)__shfl_xor((int)m1[na], off);
            uint32_t o2 = (uint32_t)__shfl_xor((int)m2[na], off);
            m2[na] = min(min(m2[na], o2), max(m1[na], o1));
            m1[na] = min(m1[na], o1);
        }
    }

    if (lg == 0) {
#pragma unroll
        for (int na = 0; na < 4; ++na) {
            uint2 w; w.x = m1[na]; w.y = m2[na];
            wred[na * 16 + l15][wv] = w;
        }
    }
    __syncthreads();

    // ---- cross-wave merge, zis write, LOCAL flagging ----
    if (tid < NPB) {
        uint32_t c1 = 0xFFFFFFFFu, c2 = 0xFFFFFFFFu;
#pragma unroll
        for (int w = 0; w < 4; ++w) {
            uint2 v = wred[tid][w];
            c2 = min(c2, min(v.y, max(c1, v.x)));
            c1 = min(c1, v.x);
        }
        const int idx = (int)(c1 & 1023u);
        sfin[tid] = idx;
        out[n0g + tid] = (float)idx;
        if ((c2 >> 10) - (c1 >> 10) < ILIM) {
            int p = atomicAdd(&ambcnt, 1);
            amblist[p] = tid;
        }
    }
    __syncthreads();

    // ---- inline exact rescreen (coalesced cbT path, r14-validated) ----
    const int namb = ambcnt;
    if (namb > 0) {
        const float* cnorm = (const float*)(ws + WS_CNORM);
        float* zrow = (float*)zs + wv * 64;       // staging region is dead
        for (int i = wv; i < namb; i += 4) {
            const int nloc = amblist[i];
            const int n  = n0g + nloc;
            const int hw = hw0 + nloc;
            float zc = in[(((size_t)(b * CDIM + lane)) << 12) + hw];
            // bit-exact numpy pairwise znorm via shfl (r7-validated)
            float sq = zc * zc;
            float accp = sq;
#pragma unroll
            for (int i2 = 1; i2 < 8; ++i2)
                accp = accp + __shfl(sq, i2 * 8 + (lane & 7));
            float t1 = accp + __shfl_xor(accp, 1);
            float t2 = t1 + __shfl_xor(t1, 2);
            float t3 = t2 + __shfl_xor(t2, 4);
            const float zn = __shfl(t3, 0);
            zrow[lane] = zc;
            // lane owns codes j*256 + 4*lane + r; coalesced float4 columns
            f32x4 acc0 = {0.f,0.f,0.f,0.f}, acc1 = {0.f,0.f,0.f,0.f};
            f32x4 acc2 = {0.f,0.f,0.f,0.f}, acc3 = {0.f,0.f,0.f,0.f};
#pragma unroll 4
            for (int c = 0; c < CDIM; ++c) {
                const float zv = zrow[c];
                const float* col = cbT + c * 1024 + 4 * lane;
                f32x4 q0 = *(const f32x4*)(col);
                f32x4 q1 = *(const f32x4*)(col + 256);
                f32x4 q2 = *(const f32x4*)(col + 512);
                f32x4 q3 = *(const f32x4*)(col + 768);
#pragma unroll
                for (int r = 0; r < 4; ++r) {
                    acc0[r] = fmaf(zv, q0[r], acc0[r]);
                    acc1[r] = fmaf(zv, q1[r], acc1[r]);
                    acc2[r] = fmaf(zv, q2[r], acc2[r]);
                    acc3[r] = fmaf(zv, q3[r], acc3[r]);
                }
            }
            unsigned long long bestk = ~0ull;
#pragma unroll
            for (int j = 0; j < 4; ++j) {
                const f32x4 cnv = *(const f32x4*)(cnorm + j * 256 + 4 * lane);
                const f32x4 acc = (j == 0) ? acc0 : (j == 1) ? acc1
                                 : (j == 2) ? acc2 : acc3;
#pragma unroll
                for (int r = 0; r < 4; ++r) {
                    const int k = j * 256 + 4 * lane + r;
                    float t = zn + cnv[r];     // fl(znorm + cnorm)
                    float u = 2.0f * acc[r];   // fl(2*dot)
                    float d = t - u;           // fl(t - u)
                    unsigned long long key =
                        ((unsigned long long)__float_as_uint(d) << 10) | (unsigned)k;
                    bestk = key < bestk ? key : bestk;
                }
            }
#pragma unroll
            for (int off = 32; off >= 1; off >>= 1) {
                unsigned long long o = shflxor64(bestk, off);
                bestk = o < bestk ? o : bestk;
            }
            if (lane == 0) {
                const int idx = (int)(bestk & 1023u);
                out[n] = (float)idx;
                sfin[nloc] = idx;
            }
        }
    }
    __syncthreads();

    if (carve && b == 15) return;   // carved image: patch rebuilds it

    // ---- zqs epilogue: gather via corrected sfin -> tile -> BCHW ----
    float (*tile)[65] = (float (*)[65])zs;
    {
        const int p = tid >> 2, q4 = tid & 3;   // 4 threads/row, 16 ch each
        const int idx = sfin[p];
        const float4* row = (const float4*)(cb + (size_t)idx * CDIM) + q4 * 4;
#pragma unroll
        for (int i = 0; i < 4; ++i) {
            float4 v = row[i];
            const int cch = q4 * 16 + i * 4;
            tile[p][cch + 0] = v.x; tile[p][cch + 1] = v.y;
            tile[p][cch + 2] = v.z; tile[p][cch + 3] = v.w;
        }
    }
    __syncthreads();
    {
        float* zq = out + NPOS + (((size_t)b * CDIM) << 12) + hw0;
#pragma unroll
        for (int i = 0; i < 16; ++i) {
            const int cch = i * 4 + wv;
            zq[((size_t)cch << 12) + lane] = tile[lane][cch];
        }
    }
}

// ---- K3 (carve fallback only): rebuild b=15 zqs image from final zis ----
__global__ __launch_bounds__(256) void vq_patch_kernel(
    const float* __restrict__ cb, float* __restrict__ out) {
    const int tid  = threadIdx.x;
    const int lane = tid & 63;
    const int wv   = tid >> 6;
    const int p0   = CARVE_N0 + blockIdx.x * 64;   // grid = 64 blocks
    const int hw0  = p0 & 4095;

    __shared__ float tile[64][65];
    __shared__ int sfin[64];
    if (tid < 64) sfin[tid] = (int)out[p0 + tid];
    __syncthreads();
    {
        const int p = tid >> 2, q4 = tid & 3;
        const int idx = sfin[p];
        const float4* row = (const float4*)(cb + (size_t)idx * CDIM) + q4 * 4;
#pragma unroll
        for (int i = 0; i < 4; ++i) {
            float4 v = row[i];
            const int cch = q4 * 16 + i * 4;
            tile[p][cch + 0] = v.x; tile[p][cch + 1] = v.y;
            tile[p][cch + 2] = v.z; tile[p][cch + 3] = v.w;
        }
    }
    __syncthreads();
    {
        float* zq = out + NPOS + (((size_t)15 * CDIM) << 12) + hw0;
#pragma unroll
        for (int i = 0; i < 16; ++i) {
            const int cch = i * 4 + wv;
            zq[((size_t)cch << 12) + lane] = tile[lane][cch];
        }
    }
}

extern "C" void kernel_launch(void* const* d_in, const int* in_sizes, int n_in,
                              void* d_out, int out_size, void* d_ws, size_t ws_size,
                              hipStream_t stream) {
    const float* in = (const float*)d_in[0];   // 16*64*64*64
    const float* cb = (const float*)d_in[1];   // 1024*64
    float* out = (float*)d_out;                // 65536 + 4194304
    unsigned char* ws = (unsigned char*)d_ws;

    const int carve = (ws_size < (size_t)WS_CBT_NEED) ? 1 : 0;
    float* cbt = carve ? (out + CBT0) : (float*)(ws + WS_CBT);

    vq_prep_kernel<<<16, 64, 0, stream>>>(cb, ws, cbt);
    vq_filter_kernel<<<NPOS / NPB, 256, 0, stream>>>(in, cb, ws, out, cbt, carve);
    if (carve)
        vq_patch_kernel<<<64, 256, 0, stream>>>(cb, out);
}